// Round 6
// baseline (134.408 us; speedup 1.0000x reference)
//
#include <hip/hip_runtime.h>
#include <math.h>

#define N_GRAPHS 4096
#define LATENT 32

typedef float v2f __attribute__((ext_vector_type(2)));

// one DPP-accumulate step; CTRL/RM must be compile-time
template<int CTRL, int RM>
__device__ __forceinline__ float dpp_add_step(float x) {
    int y = __builtin_amdgcn_update_dpp(0, __float_as_int(x), CTRL, RM, 0xf, false);
    return x + __int_as_float(y);
}
// full wave64 sum; result valid in lane 63
__device__ __forceinline__ float wave_sum64(float x) {
    x = dpp_add_step<0x111, 0xf>(x);  // row_shr:1
    x = dpp_add_step<0x112, 0xf>(x);  // row_shr:2
    x = dpp_add_step<0x114, 0xf>(x);  // row_shr:4
    x = dpp_add_step<0x118, 0xf>(x);  // row_shr:8
    x = dpp_add_step<0x142, 0xa>(x);  // row_bcast:15 -> rows 1,3
    x = dpp_add_step<0x143, 0xc>(x);  // row_bcast:31 -> rows 2,3
    return x;
}

// Zero the 33*N_GRAPHS-float accumulator workspace
__global__ __launch_bounds__(256) void zero_ws_kernel(float4* __restrict__ ws) {
    ws[blockIdx.x * 256 + threadIdx.x] = float4{0.f, 0.f, 0.f, 0.f};
}

// Fused: per-node attention score + exp + segmented (sorted-batch) weighted sums.
// KEY register-pressure fix vs r5: hidden layer split into two j-passes of 16.
// Peak live set = zr[32] + acc2[8 v2f = 16] + temps ~= 56 VGPRs -> no
// AGPR/scratch shuffling (r3/r4 compiled to 36 VGPRs and moved the overflow
// through VALU spill traffic, ~2.7x instruction inflation).
__global__ __launch_bounds__(256, 4) void attn_seg_kernel(
    const float* __restrict__ z, const int* __restrict__ batch,
    const float* __restrict__ w1, const float* __restrict__ b1,
    const float* __restrict__ w2, const float* __restrict__ b2,
    float* __restrict__ se, float* __restrict__ sez, int n)
{
    int i = blockIdx.x * blockDim.x + threadIdx.x;
    int lane = threadIdx.x & 63;
    int iL = (i < n) ? i : (n - 1);       // clamp: extra lanes contribute e=0
    int g = batch[iL];

    float zr[32];
    const float4* zp = reinterpret_cast<const float4*>(z + (size_t)iL * LATENT);
    #pragma unroll
    for (int q = 0; q < 8; ++q) {
        float4 t = zp[q];
        zr[4*q+0] = t.x; zr[4*q+1] = t.y; zr[4*q+2] = t.z; zr[4*q+3] = t.w;
    }

    // alpha = tanh(z@W1 + b1) @ w2 + b2, two passes of 16 hidden units each
    const v2f* b1v = reinterpret_cast<const v2f*>(b1);
    const v2f* w2v = reinterpret_cast<const v2f*>(w2);
    v2f alpha2 = {0.f, 0.f};
    #pragma unroll
    for (int half = 0; half < 2; ++half) {
        v2f acc2[8];
        #pragma unroll
        for (int jp = 0; jp < 8; ++jp) acc2[jp] = b1v[half*8 + jp];
        #pragma unroll
        for (int k = 0; k < LATENT; ++k) {
            v2f zk2 = {zr[k], zr[k]};
            const v2f* wr = reinterpret_cast<const v2f*>(w1 + k*LATENT + half*16);
            #pragma unroll
            for (int jp = 0; jp < 8; ++jp)
                acc2[jp] = __builtin_elementwise_fma(zk2, wr[jp], acc2[jp]);
        }
        // tanh + w2 dot for this half; acc2 dies here
        #pragma unroll
        for (int jp = 0; jp < 8; ++jp) {
            v2f x = acc2[jp];
            x.x = fminf(fmaxf(x.x, -15.f), 15.f);
            x.y = fminf(fmaxf(x.y, -15.f), 15.f);
            float ex = __expf(2.f * x.x);
            float ey = __expf(2.f * x.y);
            v2f th;
            th.x = (ex - 1.f) * __builtin_amdgcn_rcpf(ex + 1.f);
            th.y = (ey - 1.f) * __builtin_amdgcn_rcpf(ey + 1.f);
            alpha2 = __builtin_elementwise_fma(th, w2v[half*8 + jp], alpha2);
        }
    }
    float alpha = alpha2.x + alpha2.y + b2[0];
    // global-max subtraction cancels in the per-graph normalization; skip it.
    float e = (i < n) ? __expf(alpha) : 0.f;

    float v[33];
    v[0] = e;
    #pragma unroll
    for (int k = 0; k < LATENT; ++k) v[k+1] = e * zr[k];   // last use of zr

    // fast path: whole wave in one graph (batch sorted; avg run ~488 >> 64)
    bool uniform = (__shfl(g, 0) == __shfl(g, 63));
    if (uniform) {
        #pragma unroll
        for (int t = 0; t < 33; ++t) v[t] = wave_sum64(v[t]);
        if (lane == 63) {
            atomicAdd(&se[g], v[0]);
            #pragma unroll
            for (int k = 0; k < LATENT; ++k)
                atomicAdd(&sez[g*LATENT + k], v[k+1]);
        }
    } else {
        // segmented inclusive scan over the wave
        #pragma unroll
        for (int s = 1; s < 64; s <<= 1) {
            int gprev = __shfl_up(g, s);
            float m = ((lane >= s) && (gprev == g)) ? 1.f : 0.f;
            #pragma unroll
            for (int t = 0; t < 33; ++t) {
                float vv = __shfl_up(v[t], s);
                v[t] = fmaf(m, vv, v[t]);
            }
        }
        int gnext = __shfl_down(g, 1);
        bool tail = (lane == 63) || (gnext != g);
        if (tail) {
            atomicAdd(&se[g], v[0]);
            #pragma unroll
            for (int k = 0; k < LATENT; ++k)
                atomicAdd(&sez[g*LATENT + k], v[k+1]);
        }
    }
}

// One wave per graph: graph_z = sez/(se+1e-8); 32->128->64->1 MLP with sigmoid.
__global__ __launch_bounds__(64) void mlp_kernel(
    const float* __restrict__ se, const float* __restrict__ sez,
    const float* __restrict__ m1w, const float* __restrict__ m1b,
    const float* __restrict__ m2w, const float* __restrict__ m2b,
    const float* __restrict__ m3w, const float* __restrict__ m3b,
    float* __restrict__ out)
{
    int gidx = blockIdx.x;
    int lane = threadIdx.x;
    float inv = 1.f / (se[gidx] + 1e-8f);
    float gz = (lane < LATENT) ? sez[gidx*LATENT + lane] * inv : 0.f;

    float a0 = m1b[lane], a1 = m1b[lane + 64];
    #pragma unroll
    for (int k = 0; k < LATENT; ++k) {
        float zk = __shfl(gz, k);
        a0 = fmaf(zk, m1w[k*128 + lane], a0);
        a1 = fmaf(zk, m1w[k*128 + lane + 64], a1);
    }
    a0 = fmaxf(a0, 0.f); a1 = fmaxf(a1, 0.f);

    float b = m2b[lane];
    #pragma unroll
    for (int k = 0; k < 64; ++k) {
        float xk = __shfl(a0, k);
        b = fmaf(xk, m2w[k*64 + lane], b);
    }
    #pragma unroll
    for (int k = 0; k < 64; ++k) {
        float xk = __shfl(a1, k);
        b = fmaf(xk, m2w[(k+64)*64 + lane], b);
    }
    b = fmaxf(b, 0.f);

    float p = b * m3w[lane];
    #pragma unroll
    for (int s = 32; s >= 1; s >>= 1)
        p += __shfl_xor(p, s);
    if (lane == 0)
        out[gidx] = 1.f / (1.f + __expf(-(p + m3b[0])));
}

extern "C" void kernel_launch(void* const* d_in, const int* in_sizes, int n_in,
                              void* d_out, int out_size, void* d_ws, size_t ws_size,
                              hipStream_t stream)
{
    const float* z    = (const float*)d_in[0];
    const int*   batch= (const int*)d_in[1];
    const float* aw1  = (const float*)d_in[2];
    const float* ab1  = (const float*)d_in[3];
    const float* aw2  = (const float*)d_in[4];
    const float* ab2  = (const float*)d_in[5];
    const float* m1w  = (const float*)d_in[6];
    const float* m1b  = (const float*)d_in[7];
    const float* m2w  = (const float*)d_in[8];
    const float* m2b  = (const float*)d_in[9];
    const float* m3w  = (const float*)d_in[10];
    const float* m3b  = (const float*)d_in[11];
    float* out = (float*)d_out;

    int n = in_sizes[0] / LATENT;   // 2,000,000 nodes

    float* se  = (float*)d_ws;          // [4096]
    float* sez = se + N_GRAPHS;         // [4096][32]

    // N_GRAPHS*33 floats = 135168 floats = 33792 float4 = 132 blocks * 256
    zero_ws_kernel<<<132, 256, 0, stream>>>((float4*)d_ws);

    int blocks = (n + 255) / 256;
    attn_seg_kernel<<<blocks, 256, 0, stream>>>(z, batch, aw1, ab1, aw2, ab2, se, sez, n);
    mlp_kernel<<<N_GRAPHS, 64, 0, stream>>>(se, sez, m1w, m1b, m2w, m2b, m3w, m3b, out);
}

// Round 7
// 112.078 us; speedup vs baseline: 1.1992x; 1.1992x over previous
//
#include <hip/hip_runtime.h>
#include <math.h>

#define N_GRAPHS 4096
#define LATENT 32
#define BLK 256

typedef float v2f __attribute__((ext_vector_type(2)));

// Zero the 33*N_GRAPHS-float accumulator workspace
__global__ __launch_bounds__(256) void zero_ws_kernel(float4* __restrict__ ws) {
    ws[blockIdx.x * 256 + threadIdx.x] = float4{0.f, 0.f, 0.f, 0.f};
}

// Fused: per-node attention score + exp + segmented weighted sums.
// r7 restructure: the 198-op cross-lane scan/DPP reduce + v[33] liveness spike
// is replaced by an LDS tile: thread=node writes e*z (+e) to ezs[node][33],
// then threads remap to (k, chunk) and do a k-parallel segmented sum with
// atomic flush on graph change (batch sorted -> <=2 graphs per 32-node chunk).
__global__ __launch_bounds__(BLK, 2) void attn_seg_kernel(
    const float* __restrict__ z, const int* __restrict__ batch,
    const float* __restrict__ w1, const float* __restrict__ b1,
    const float* __restrict__ w2, const float* __restrict__ b2,
    float* __restrict__ se, float* __restrict__ sez, int n)
{
    __shared__ float ezs[BLK * 33];   // [node][k]: cols 0..31 = e*z, col 32 = e
    __shared__ int   gls[BLK];        // graph id per node

    const int t  = threadIdx.x;
    const int nd = blockIdx.x * BLK + t;
    const int ndL = (nd < n) ? nd : (n - 1);   // clamp; clamped rows get e=0
    const int g = batch[ndL];
    gls[t] = g;

    float zr[32];
    const float4* zp = reinterpret_cast<const float4*>(z + (size_t)ndL * LATENT);
    #pragma unroll
    for (int q = 0; q < 8; ++q) {
        float4 v4 = zp[q];
        zr[4*q+0] = v4.x; zr[4*q+1] = v4.y; zr[4*q+2] = v4.z; zr[4*q+3] = v4.w;
    }

    // alpha = tanh(z@W1 + b1) @ w2 + b2 -- 4 passes of 8 hidden units
    // (peak live ~= zr[32] + acc[8] + temps: no spill pressure)
    float alpha = b2[0];
    #pragma unroll
    for (int p = 0; p < 4; ++p) {
        v2f acc[4];
        const v2f* b1v = reinterpret_cast<const v2f*>(b1 + p*8);
        #pragma unroll
        for (int a = 0; a < 4; ++a) acc[a] = b1v[a];
        #pragma unroll
        for (int k = 0; k < LATENT; ++k) {
            const v2f zk2 = {zr[k], zr[k]};
            const v2f* wr = reinterpret_cast<const v2f*>(w1 + k*LATENT + p*8);
            #pragma unroll
            for (int a = 0; a < 4; ++a)
                acc[a] = __builtin_elementwise_fma(zk2, wr[a], acc[a]);
        }
        // tanh(x) = 1 - 2/(exp(2x)+1); +/-inf limits give +/-1 exactly, no clamp
        #pragma unroll
        for (int a = 0; a < 4; ++a) {
            #pragma unroll
            for (int u = 0; u < 2; ++u) {
                float x  = (u == 0) ? acc[a].x : acc[a].y;
                float e2 = __expf(2.f * x);
                float th = 1.f - 2.f * __builtin_amdgcn_rcpf(e2 + 1.f);
                alpha = fmaf(th, w2[p*8 + a*2 + u], alpha);
            }
        }
    }
    // global-max subtraction cancels in per-graph normalization; skip it.
    float e = (nd < n) ? __expf(alpha) : 0.f;

    // stage e*z and e; row stride 33 words -> bank (t+k)%32, 2-way = free
    float* row = ezs + t * 33;
    #pragma unroll
    for (int k = 0; k < LATENT; ++k) row[k] = e * zr[k];
    row[32] = e;
    __syncthreads();

    // k-parallel segmented reduce: 8 chunks x 32 nodes, lane k sums column k
    {
        const int k = t & 31, base = (t >> 5) * 32;
        float acc = 0.f;
        int gc = gls[base];
        #pragma unroll
        for (int j = 0; j < 32; ++j) {
            int gn = gls[base + j];
            float val = ezs[(base + j) * 33 + k];
            if (gn != gc) {                       // uniform within a chunk
                atomicAdd(&sez[gc * LATENT + k], acc);
                acc = 0.f; gc = gn;
            }
            acc += val;
        }
        atomicAdd(&sez[gc * LATENT + k], acc);
    }
    // se: 8 lanes sweep the e column (col 32), same flush logic
    if (t < 8) {
        const int base = t * 32;
        float acc = 0.f;
        int gc = gls[base];
        #pragma unroll
        for (int j = 0; j < 32; ++j) {
            int gn = gls[base + j];
            float val = ezs[(base + j) * 33 + 32];
            if (gn != gc) { atomicAdd(&se[gc], acc); acc = 0.f; gc = gn; }
            acc += val;
        }
        atomicAdd(&se[gc], acc);
    }
}

// One wave per graph: graph_z = sez/(se+1e-8); 32->128->64->1 MLP with sigmoid.
__global__ __launch_bounds__(64) void mlp_kernel(
    const float* __restrict__ se, const float* __restrict__ sez,
    const float* __restrict__ m1w, const float* __restrict__ m1b,
    const float* __restrict__ m2w, const float* __restrict__ m2b,
    const float* __restrict__ m3w, const float* __restrict__ m3b,
    float* __restrict__ out)
{
    int gidx = blockIdx.x;
    int lane = threadIdx.x;
    float inv = 1.f / (se[gidx] + 1e-8f);
    float gz = (lane < LATENT) ? sez[gidx*LATENT + lane] * inv : 0.f;

    float a0 = m1b[lane], a1 = m1b[lane + 64];
    #pragma unroll
    for (int k = 0; k < LATENT; ++k) {
        float zk = __shfl(gz, k);
        a0 = fmaf(zk, m1w[k*128 + lane], a0);
        a1 = fmaf(zk, m1w[k*128 + lane + 64], a1);
    }
    a0 = fmaxf(a0, 0.f); a1 = fmaxf(a1, 0.f);

    float b = m2b[lane];
    #pragma unroll
    for (int k = 0; k < 64; ++k) {
        float xk = __shfl(a0, k);
        b = fmaf(xk, m2w[k*64 + lane], b);
    }
    #pragma unroll
    for (int k = 0; k < 64; ++k) {
        float xk = __shfl(a1, k);
        b = fmaf(xk, m2w[(k+64)*64 + lane], b);
    }
    b = fmaxf(b, 0.f);

    float p = b * m3w[lane];
    #pragma unroll
    for (int s = 32; s >= 1; s >>= 1)
        p += __shfl_xor(p, s);
    if (lane == 0)
        out[gidx] = 1.f / (1.f + __expf(-(p + m3b[0])));
}

extern "C" void kernel_launch(void* const* d_in, const int* in_sizes, int n_in,
                              void* d_out, int out_size, void* d_ws, size_t ws_size,
                              hipStream_t stream)
{
    const float* z    = (const float*)d_in[0];
    const int*   batch= (const int*)d_in[1];
    const float* aw1  = (const float*)d_in[2];
    const float* ab1  = (const float*)d_in[3];
    const float* aw2  = (const float*)d_in[4];
    const float* ab2  = (const float*)d_in[5];
    const float* m1w  = (const float*)d_in[6];
    const float* m1b  = (const float*)d_in[7];
    const float* m2w  = (const float*)d_in[8];
    const float* m2b  = (const float*)d_in[9];
    const float* m3w  = (const float*)d_in[10];
    const float* m3b  = (const float*)d_in[11];
    float* out = (float*)d_out;

    int n = in_sizes[0] / LATENT;   // 2,000,000 nodes

    float* se  = (float*)d_ws;          // [4096]
    float* sez = se + N_GRAPHS;         // [4096][32]

    // N_GRAPHS*33 floats = 135168 floats = 33792 float4 = 132 blocks * 256
    zero_ws_kernel<<<132, 256, 0, stream>>>((float4*)d_ws);

    int blocks = (n + BLK - 1) / BLK;
    attn_seg_kernel<<<blocks, BLK, 0, stream>>>(z, batch, aw1, ab1, aw2, ab2, se, sez, n);
    mlp_kernel<<<N_GRAPHS, 64, 0, stream>>>(se, sez, m1w, m1b, m2w, m2b, m3w, m3b, out);
}